// Round 2
// baseline (180.431 us; speedup 1.0000x reference)
//
#include <hip/hip_runtime.h>
#include <math.h>

// pred/targ: f32 [B=4096, H=128, D=64]; out: scalar f32.
//
// Only row h = idx (idx = t-1, or H-1 if t==0) of (loss+loss1) contributes
// per sample, where t = count_nonzero(targ[i,:,1]).
//   total[i,idx,d] = diff^2 + |diff - prev_diff|
//   per_sample[i]  = (1 + 0.5*(t/(H-1))^2.5) * sum_d total[i,idx,d]
//   out = mean_i per_sample[i]
//
// Single fused kernel: 2 samples per 256-thread block; last block (via
// atomic ticket) reduces per_sample[] in fixed order -> deterministic.

#define H_DIM 128
#define D_DIM 64

__global__ __launch_bounds__(256) void wsl_fused_kernel(
    const float* __restrict__ pred,
    const float* __restrict__ targ,
    float* __restrict__ per_sample,      // [B] scratch
    unsigned int* __restrict__ ticket,   // [1], zeroed before launch
    float* __restrict__ out,
    int B, int nblocks)
{
    const int tid     = threadIdx.x;     // 0..255
    const int s_local = tid >> 7;        // 0 or 1: which sample in this block
    const int lane128 = tid & 127;       // h index within the sample's column
    const int i       = blockIdx.x * 2 + s_local;
    const long long base = (long long)i * (H_DIM * D_DIM);

    // ---- phase 1: t = nnz(targ[i, :, 1]) ----
    // waves 0,1 -> sample s_local=0 ; waves 2,3 -> sample s_local=1
    const float v = targ[base + (long long)lane128 * D_DIM + 1];
    const unsigned long long mask = __ballot(v != 0.0f);

    __shared__ int wave_cnt[4];
    __shared__ unsigned int is_last;
    __shared__ float sred[256];

    if ((tid & 63) == 0) wave_cnt[tid >> 6] = __popcll(mask);
    __syncthreads();
    const int t = wave_cnt[s_local * 2] + wave_cnt[s_local * 2 + 1];

    int idx = t - 1;
    if (idx < 0) idx = H_DIM - 1;        // torch negative-index mimic

    // ---- phase 2: row reduction over d (waves 0 and 2 only) ----
    if ((tid & 64) == 0) {
        const int lane = tid & 63;
        const long long off = base + (long long)idx * D_DIM + lane;
        const float dcur = pred[off] - targ[off];
        float dprev = 0.0f;
        if (idx >= 1) dprev = pred[off - D_DIM] - targ[off - D_DIM];
        float sum = dcur * dcur + fabsf(dcur - dprev);

        #pragma unroll
        for (int sh = 32; sh >= 1; sh >>= 1)
            sum += __shfl_down(sum, sh, 64);

        if (lane == 0) {
            const float tf = (float)t / (float)(H_DIM - 1);
            const float w  = 1.0f + 0.5f * powf(tf, 2.5f);
            per_sample[i] = w * sum;
        }
    }

    // ---- last-block reduction (threadfence reduction pattern) ----
    __threadfence();                      // make per_sample stores device-visible
    __syncthreads();
    if (tid == 0) {
        const unsigned int rank = atomicAdd(ticket, 1u);
        is_last = (rank == (unsigned int)(nblocks - 1)) ? 1u : 0u;
    }
    __syncthreads();

    if (is_last) {
        __threadfence();                  // acquire side
        float acc = 0.0f;
        for (int j = tid; j < B; j += 256) acc += per_sample[j];  // fixed order
        sred[tid] = acc;
        __syncthreads();
        #pragma unroll
        for (int st = 128; st >= 1; st >>= 1) {
            if (tid < st) sred[tid] += sred[tid + st];
            __syncthreads();
        }
        if (tid == 0) out[0] = sred[0] / (float)B;
    }
}

extern "C" void kernel_launch(void* const* d_in, const int* in_sizes, int n_in,
                              void* d_out, int out_size, void* d_ws, size_t ws_size,
                              hipStream_t stream)
{
    const float* pred = (const float*)d_in[0];
    const float* targ = (const float*)d_in[1];
    float* out = (float*)d_out;

    const int B = in_sizes[0] / (H_DIM * D_DIM);   // 4096

    float* per_sample    = (float*)d_ws;           // B floats
    unsigned int* ticket = (unsigned int*)(per_sample + B);

    hipMemsetAsync(ticket, 0, sizeof(unsigned int), stream);

    const int nblocks = B / 2;                     // 2048
    wsl_fused_kernel<<<nblocks, 256, 0, stream>>>(
        pred, targ, per_sample, ticket, out, B, nblocks);
}

// Round 3
// 23.447 us; speedup vs baseline: 7.6952x; 7.6952x over previous
//
#include <hip/hip_runtime.h>
#include <math.h>

// pred/targ: f32 [B=4096, H=128, D=64]; out: scalar f32.
//
// Only row h = idx (idx = t-1, or H-1 if t==0) of (loss+loss1) contributes
// per sample, where t = count_nonzero(targ[i,:,1]).
//   total[i,idx,d] = diff^2 + |diff - prev_diff|
//   per_sample[i]  = (1 + 0.5*(t/(H-1))^2.5) * sum_d total[i,idx,d]
//   out = mean_i per_sample[i]
//
// Stage 1: 512 blocks x 256 threads, 8 samples/block, one partial sum/block.
//   phase 1: 4 independent strided column loads per thread (ILP: one
//            memory round-trip covers all 8 samples' nnz counts)
//   phase 2: each wave reduces 2 sample rows (independent, unrolled)
// Stage 2: one wave reduces the 512 partials. All sums in fixed order
// (deterministic). No device fences, no global atomics (R2 lesson: per-block
// __threadfence on CDNA4 forces cross-XCD L2 writeback -> 10x regression).

#define H_DIM 128
#define D_DIM 64
#define SPB   8     // samples per block

__global__ __launch_bounds__(256) void wsl_stage1(
    const float* __restrict__ pred,
    const float* __restrict__ targ,
    float* __restrict__ block_sums)       // [gridDim.x]
{
    const int tid  = threadIdx.x;         // 0..255
    const int wave = tid >> 6;            // 0..3
    const int lane = tid & 63;
    const int s0   = blockIdx.x * SPB;    // first sample of this block

    // ---- phase 1: issue all 4 column loads (8 samples) back-to-back ----
    // iteration k covers samples s0 + 2k + (tid>>7); h = tid & 127
    float colv[4];
    #pragma unroll
    for (int k = 0; k < 4; ++k) {
        const int s = s0 + 2 * k + (tid >> 7);
        const long long base = (long long)s * (H_DIM * D_DIM);
        colv[k] = targ[base + (long long)(tid & 127) * D_DIM + 1];
    }

    // ballots: in iteration k, wave w holds sample (2k + (w>>1)),
    // h-range [ (w&1)*64 , (w&1)*64+63 ]
    __shared__ int cnt[4][4];             // [k][wave]
    __shared__ float samp[SPB];
    #pragma unroll
    for (int k = 0; k < 4; ++k) {
        const unsigned long long m = __ballot(colv[k] != 0.0f);
        if (lane == 0) cnt[k][wave] = __popcll(m);
    }
    __syncthreads();

    // ---- phase 2: each wave reduces rows of samples j = wave, wave+4 ----
    #pragma unroll
    for (int r = 0; r < 2; ++r) {
        const int j = wave + 4 * r;                    // 0..7
        // t for sample j: stored in cnt[j>>1][(j&1)*2 .. (j&1)*2+1]
        const int t = cnt[j >> 1][(j & 1) * 2] + cnt[j >> 1][(j & 1) * 2 + 1];
        int idx = t - 1;
        if (idx < 0) idx = H_DIM - 1;                  // torch negative-index mimic

        const long long base = (long long)(s0 + j) * (H_DIM * D_DIM);
        const long long off  = base + (long long)idx * D_DIM + lane;
        const float dcur = pred[off] - targ[off];
        float dprev = 0.0f;
        if (idx >= 1) dprev = pred[off - D_DIM] - targ[off - D_DIM];
        float sum = dcur * dcur + fabsf(dcur - dprev);

        #pragma unroll
        for (int sh = 32; sh >= 1; sh >>= 1)
            sum += __shfl_down(sum, sh, 64);

        if (lane == 0) {
            const float tf = (float)t / (float)(H_DIM - 1);
            samp[j] = (1.0f + 0.5f * powf(tf, 2.5f)) * sum;
        }
    }
    __syncthreads();

    if (tid == 0) {
        float a = 0.0f;
        #pragma unroll
        for (int j = 0; j < SPB; ++j) a += samp[j];    // fixed order
        block_sums[blockIdx.x] = a;
    }
}

__global__ __launch_bounds__(64) void wsl_stage2(
    const float* __restrict__ block_sums,
    float* __restrict__ out,
    int n, float invB)
{
    const int lane = threadIdx.x;
    float acc = 0.0f;
    for (int j = lane; j < n; j += 64) acc += block_sums[j];  // fixed order
    #pragma unroll
    for (int sh = 32; sh >= 1; sh >>= 1)
        acc += __shfl_down(acc, sh, 64);
    if (lane == 0) out[0] = acc * invB;
}

extern "C" void kernel_launch(void* const* d_in, const int* in_sizes, int n_in,
                              void* d_out, int out_size, void* d_ws, size_t ws_size,
                              hipStream_t stream)
{
    const float* pred = (const float*)d_in[0];
    const float* targ = (const float*)d_in[1];
    float* out = (float*)d_out;

    const int B = in_sizes[0] / (H_DIM * D_DIM);   // 4096
    const int nblocks = B / SPB;                   // 512

    float* block_sums = (float*)d_ws;              // nblocks floats

    wsl_stage1<<<nblocks, 256, 0, stream>>>(pred, targ, block_sums);
    wsl_stage2<<<1, 64, 0, stream>>>(block_sums, out, nblocks, 1.0f / (float)B);
}

// Round 4
// 21.708 us; speedup vs baseline: 8.3116x; 1.0801x over previous
//
#include <hip/hip_runtime.h>
#include <math.h>

// pred/targ: f32 [B=4096, H=128, D=64]; out: scalar f32.
//
// per_sample[i] = (1 + 0.5*(t/(H-1))^2.5) * sum_d( diff^2 + |diff - prev_diff| )
//   at row idx = t-1 (H-1 if t==0), t = nnz(targ[i,:,1]),
//   diff = pred[i,idx,:]-targ[i,idx,:], prev_diff = row idx-1 (0 if idx==0).
// out = mean_i per_sample[i]
//
// R4: value speculation. For gaussian targ, t==128 always -> rows 127/126.
// Issue those row loads CONCURRENTLY with the column loads (independent
// addresses), then branch wave-uniformly on t==128: fast path uses the
// preloaded rows (ONE memory round-trip per block instead of two serial);
// slow path (any other input) does the dependent load as before.
// Two dispatches kept: per-block device fences / grid.sync cost ~100ns
// serialized on CDNA4 (R2: 2048 fences -> 180us), kernel boundary is cheaper.

#define H_DIM 128
#define D_DIM 64
#define SPB   8     // samples per block

__global__ __launch_bounds__(256) void wsl_stage1(
    const float* __restrict__ pred,
    const float* __restrict__ targ,
    float* __restrict__ block_sums)       // [gridDim.x]
{
    const int tid  = threadIdx.x;         // 0..255
    const int wave = tid >> 6;            // 0..3
    const int lane = tid & 63;
    const int s0   = blockIdx.x * SPB;    // first sample of this block

    // ---- phase 1a: 4 column loads (8 samples' nnz columns), independent ----
    float colv[4];
    #pragma unroll
    for (int k = 0; k < 4; ++k) {
        const int s = s0 + 2 * k + (tid >> 7);
        const long long base = (long long)s * (H_DIM * D_DIM);
        colv[k] = targ[base + (long long)(tid & 127) * D_DIM + 1];
    }

    // ---- phase 1b: speculative row loads for the common case t==128 ----
    // (rows 127 and 126 of the 2 samples this wave will reduce; independent
    //  of phase 1a results -> same memory round-trip)
    float sp_pc[2], sp_tc[2], sp_pp[2], sp_tp[2];
    #pragma unroll
    for (int r = 0; r < 2; ++r) {
        const int j = wave + 4 * r;
        const long long base = (long long)(s0 + j) * (H_DIM * D_DIM);
        sp_pc[r] = pred[base + 127 * D_DIM + lane];
        sp_tc[r] = targ[base + 127 * D_DIM + lane];
        sp_pp[r] = pred[base + 126 * D_DIM + lane];
        sp_tp[r] = targ[base + 126 * D_DIM + lane];
    }

    // ballots: iteration k covers sample 2k+(wave>>1); wave parity = h-half
    __shared__ int cnt[4][4];             // [k][wave]
    __shared__ float samp[SPB];
    #pragma unroll
    for (int k = 0; k < 4; ++k) {
        const unsigned long long m = __ballot(colv[k] != 0.0f);
        if (lane == 0) cnt[k][wave] = __popcll(m);
    }
    __syncthreads();

    // ---- phase 2: each wave reduces rows of samples j = wave, wave+4 ----
    #pragma unroll
    for (int r = 0; r < 2; ++r) {
        const int j = wave + 4 * r;                    // 0..7
        const int t = cnt[j >> 1][(j & 1) * 2] + cnt[j >> 1][(j & 1) * 2 + 1];

        float dcur, dprev;
        if (t == H_DIM) {
            // fast path: speculation hit (idx = 127, prev = 126)
            dcur  = sp_pc[r] - sp_tc[r];
            dprev = sp_pp[r] - sp_tp[r];
        } else {
            // general path: dependent load (wave-uniform branch)
            int idx = t - 1;
            if (idx < 0) idx = H_DIM - 1;              // torch negative-index mimic
            const long long base = (long long)(s0 + j) * (H_DIM * D_DIM);
            const long long off  = base + (long long)idx * D_DIM + lane;
            dcur  = pred[off] - targ[off];
            dprev = 0.0f;
            if (idx >= 1) dprev = pred[off - D_DIM] - targ[off - D_DIM];
        }
        float sum = dcur * dcur + fabsf(dcur - dprev);

        #pragma unroll
        for (int sh = 32; sh >= 1; sh >>= 1)
            sum += __shfl_down(sum, sh, 64);

        if (lane == 0) {
            const float tf = (float)t / (float)(H_DIM - 1);
            samp[j] = (1.0f + 0.5f * powf(tf, 2.5f)) * sum;
        }
    }
    __syncthreads();

    if (tid == 0) {
        float a = 0.0f;
        #pragma unroll
        for (int jj = 0; jj < SPB; ++jj) a += samp[jj];  // fixed order
        block_sums[blockIdx.x] = a;
    }
}

__global__ __launch_bounds__(256) void wsl_stage2(
    const float* __restrict__ block_sums,
    float* __restrict__ out,
    int n, float invB)
{
    __shared__ float s[256];
    const int tid = threadIdx.x;
    float a0 = (tid       < n) ? block_sums[tid]       : 0.0f;
    float a1 = (tid + 256 < n) ? block_sums[tid + 256] : 0.0f;
    s[tid] = a0 + a1;                     // two independent loads, one trip
    __syncthreads();
    #pragma unroll
    for (int st = 128; st >= 1; st >>= 1) {
        if (tid < st) s[tid] += s[tid + st];
        __syncthreads();
    }
    if (tid == 0) out[0] = s[0] * invB;
}

extern "C" void kernel_launch(void* const* d_in, const int* in_sizes, int n_in,
                              void* d_out, int out_size, void* d_ws, size_t ws_size,
                              hipStream_t stream)
{
    const float* pred = (const float*)d_in[0];
    const float* targ = (const float*)d_in[1];
    float* out = (float*)d_out;

    const int B = in_sizes[0] / (H_DIM * D_DIM);   // 4096
    const int nblocks = B / SPB;                   // 512

    float* block_sums = (float*)d_ws;              // nblocks floats

    wsl_stage1<<<nblocks, 256, 0, stream>>>(pred, targ, block_sums);
    wsl_stage2<<<1, 256, 0, stream>>>(block_sums, out, nblocks, 1.0f / (float)B);
}